// Round 12
// baseline (130.418 us; speedup 1.0000x reference)
//
#include <hip/hip_runtime.h>

#define NROWS 8192
#define DDIM  256
#define NBINS 129

typedef float f32x4 __attribute__((ext_vector_type(4)));
typedef short bf16x8 __attribute__((ext_vector_type(8)));

__device__ __forceinline__ float wave_red(float v) {
#pragma unroll
    for (int m = 32; m; m >>= 1) v += __shfl_xor(v, m, 64);
    return v;
}

__device__ __forceinline__ unsigned bfbits(float f) {
    union { float f; unsigned u; } v; v.f = f;
    return (v.u + 0x7FFFu + ((v.u >> 16) & 1u)) >> 16;
}

__device__ __forceinline__ void gload_lds16(const void* g, void* l) {
    __builtin_amdgcn_global_load_lds((const __attribute__((address_space(1))) void*)g,
                                     (__attribute__((address_space(3))) void*)l,
                                     16, 0, 0);
}

// ---------------------------------------------------------------------------
// Kernel 1: DFT basis, transposed layout basisT[288][256] bf16.
// rows 0..128: cos(2*pi*n*k/256); rows 144..272: sin; others zero.
// ---------------------------------------------------------------------------
__global__ __launch_bounds__(256) void k_basis(unsigned short* __restrict__ basisT) {
    const int n = blockIdx.x;    // 0..287
    const int k = threadIdx.x;   // 0..255
    float v = 0.0f;
    const float step = 0.0245436926f;  // 2*pi/256
    if (n < 129)                  v = cosf(step * (float)((n * k) & 255));
    else if (n >= 144 && n < 273) v = sinf(step * (float)(((n - 144) * k) & 255));
    basisT[n * DDIM + k] = (unsigned short)bfbits(v);
}

// ---------------------------------------------------------------------------
// Kernel 2 (fused row+dft): 16 rows/block.
//  phase 1: coalesced read; spatial MSE + row norms
//  phase 2: normalized bf16 write
//  phase 3: A-fragments re-read from L2-hot global
//  phase 4: DFT via MFMA vs basisT; magnitudes; frequency MSE partial
// ---------------------------------------------------------------------------
__global__ __launch_bounds__(256) void k_prep(const float* __restrict__ clean,
                                              const float* __restrict__ turb,
                                              const unsigned short* __restrict__ basisT,
                                              unsigned short* __restrict__ cnb,
                                              unsigned short* __restrict__ tnb,
                                              float* __restrict__ spat_part,
                                              float* __restrict__ freq_part) {
    __shared__ float xch[2][2][16][132];   // [src][trig][row][bin] cr/ci  (33 KB)
    __shared__ float invn[16][2];
    __shared__ float sp4[4], rbuf[4];

    const int t    = threadIdx.x;
    const int w    = t >> 6;
    const int lane = t & 63;
    const int rb   = blockIdx.x * 16;

    // ---- phase 1: coalesced load; per-row norms; spatial partial ----
    float4 xc4[4], xt4[4];
    float dsq = 0.0f;
#pragma unroll
    for (int q = 0; q < 4; ++q) {
        const int row = q * 4 + w;           // wave w owns row q*4+w
        const float* pc = clean + (rb + row) * DDIM + lane * 4;
        const float* pt = turb  + (rb + row) * DDIM + lane * 4;
        xc4[q] = *(const float4*)pc;
        xt4[q] = *(const float4*)pt;
        const float4 a = xc4[q], b = xt4[q];
        dsq += (a.x - b.x) * (a.x - b.x) + (a.y - b.y) * (a.y - b.y)
             + (a.z - b.z) * (a.z - b.z) + (a.w - b.w) * (a.w - b.w);
        float nsc = a.x * a.x + a.y * a.y + a.z * a.z + a.w * a.w;
        float nst = b.x * b.x + b.y * b.y + b.z * b.z + b.w * b.w;
        nsc = wave_red(nsc);
        nst = wave_red(nst);
        if (lane == 0) {
            invn[row][0] = 1.0f / fmaxf(sqrtf(nsc), 1e-12f);
            invn[row][1] = 1.0f / fmaxf(sqrtf(nst), 1e-12f);
        }
    }
    dsq = wave_red(dsq);
    if (lane == 0) sp4[w] = dsq;
    __syncthreads();

    // ---- phase 2: normalized bf16 writes (8B coalesced stores) ----
#pragma unroll
    for (int q = 0; q < 4; ++q) {
        const int row = q * 4 + w;
        const float ic = invn[row][0], it = invn[row][1];
        const float4 a = xc4[q], b = xt4[q];
        uint2 pc, pt;
        pc.x = bfbits(a.x * ic) | (bfbits(a.y * ic) << 16);
        pc.y = bfbits(a.z * ic) | (bfbits(a.w * ic) << 16);
        pt.x = bfbits(b.x * it) | (bfbits(b.y * it) << 16);
        pt.y = bfbits(b.z * it) | (bfbits(b.w * it) << 16);
        *(uint2*)(cnb + (rb + row) * DDIM + lane * 4) = pc;
        *(uint2*)(tnb + (rb + row) * DDIM + lane * 4) = pt;
    }

    // ---- phase 3: A-fragments from L2-hot global ----
    const int srcw = w & 1;         // 0 clean, 1 turb
    const int trig = w >> 1;        // 0 cos, 1 sin
    bf16x8 a[8];
    {
        const float* src = srcw ? turb : clean;
        const float* rowp = src + (rb + (lane & 15)) * DDIM + ((lane >> 4) << 3);
#pragma unroll
        for (int kk = 0; kk < 8; ++kk) {
            const float4 lo = *(const float4*)(rowp + kk * 32);
            const float4 hi = *(const float4*)(rowp + kk * 32 + 4);
            bf16x8 tv;
            tv[0] = (short)bfbits(lo.x); tv[1] = (short)bfbits(lo.y);
            tv[2] = (short)bfbits(lo.z); tv[3] = (short)bfbits(lo.w);
            tv[4] = (short)bfbits(hi.x); tv[5] = (short)bfbits(hi.y);
            tv[6] = (short)bfbits(hi.z); tv[7] = (short)bfbits(hi.w);
            a[kk] = tv;
        }
    }

    // ---- phase 4: DFT MFMAs ----
    const unsigned short* bbase = basisT + (trig * 144 + (lane & 15)) * DDIM
                                + ((lane >> 4) << 3);
    const int lrow = (lane >> 4) << 2;
#pragma unroll 1
    for (int n = 0; n < 9; ++n) {
        f32x4 acc = (f32x4){0.f, 0.f, 0.f, 0.f};
#pragma unroll
        for (int kk = 0; kk < 8; ++kk) {
            bf16x8 b = *(const bf16x8*)(bbase + n * 16 * DDIM + kk * 32);
            acc = __builtin_amdgcn_mfma_f32_16x16x32_bf16(a[kk], b, acc, 0, 0, 0);
        }
        const int bin = n * 16 + (lane & 15);
        if (bin <= 128) {   // GUARD: n=8 covers bins 128..143; only 128 is real.
#pragma unroll
            for (int rr = 0; rr < 4; ++rr)
                xch[srcw][trig][lrow + rr][bin] = acc[rr];
        }
    }
    __syncthreads();

    // block reduce of (|fft_c| - |fft_t|)^2 over 16 rows x 129 bins
    {
        const int rr = t >> 4;
        float s = 0.0f;
        for (int b = (t & 15); b < NBINS; b += 16) {
            const float crc = xch[0][0][rr][b], cic = xch[0][1][rr][b];
            const float crt = xch[1][0][rr][b], cit = xch[1][1][rr][b];
            const float d = sqrtf(crc * crc + cic * cic)
                          - sqrtf(crt * crt + cit * cit);
            s += d * d;
        }
        s = wave_red(s);
        if (lane == 0) rbuf[w] = s;
    }
    __syncthreads();
    if (t == 0) {
        freq_part[blockIdx.x] = rbuf[0] + rbuf[1] + rbuf[2] + rbuf[3];
        spat_part[blockIdx.x] = sp4[0] + sp4[1] + sp4[2] + sp4[3];
    }
}

// ---------------------------------------------------------------------------
// Kernel 3: 64x128 bf16 MFMA GEMM, A-IN-REGISTERS across full K (K=256 fits:
// 16 bf16x8 = 64 VGPR/wave). No A staging, no A LDS, no A ds_reads — LDS pipe
// traffic (the measured r10/r11 bottleneck, ~74% of CU cycles) drops ~1/3.
// Only B flows through LDS (16 KB, swizzled staging). Swapped-operand MFMA
// epilogue + supertile XCD swizzle unchanged. kt loop fully unrolled so all
// a[][] indices are static (no scratch).
// ---------------------------------------------------------------------------
#define BM 64
#define BN 128
#define BK 64

__global__ __launch_bounds__(256) void k_gemm(const unsigned short* __restrict__ cnb,
                                              const unsigned short* __restrict__ tnb,
                                              const int* __restrict__ sid,
                                              float* __restrict__ pall,
                                              float* __restrict__ ppos) {
    __shared__ unsigned short Bs[BN][BK];    // 16 KB
    __shared__ float ps[2][BM][2];           // [colhalf][row][all|pos]
    __shared__ int sidI[BM], sidJ[BN];

    // Supertile XCD swizzle: 8192 blocks, ib in [0,128), jb in [0,64).
    // Bijective: 8*8*128 = 8192. Per-XCD working set ~1 MB (fits 4 MB L2).
    const int bid = blockIdx.x;
    const int xcd = bid & 7;
    const int q   = bid >> 3;            // 0..1023
    const int grp = q >> 7;              // jb group 0..7
    const int r   = q & 127;
    const int ib  = xcd * 16 + (r >> 3); // 0..127
    const int jb  = grp * 8 + (r & 7);   // 0..63
    const int i0  = ib * BM;
    const int j0  = jb * BN;

    const int t = threadIdx.x;
    if (t < BM) sidI[t] = sid[i0 + t];
    else if (t < BM + BN) sidJ[t - BM] = sid[j0 + t - BM];

    const int wid  = t >> 6;
    const int lane = t & 63;
    const int wrow = (wid >> 1) * 32;    // row half: 0 / 32
    const int wcol = (wid & 1) * 64;     // col half: 0 / 64
    const int rx   = lane & 7;

    // ---- stage B tile kt=0 first (latency overlaps the A reg-loads) ----
#define STAGE_B(kt)                                                           \
    {                                                                         \
        _Pragma("unroll")                                                     \
        for (int it = 0; it < 4; ++it) {                                      \
            const int g  = it * 256 + t;                                      \
            const int rr = g >> 3;                                            \
            const int sl = g & 7;                                             \
            const int sc = ((sl ^ (rr & 7)) << 3);                            \
            gload_lds16(tnb + (j0 + rr) * DDIM + (kt) * BK + sc,              \
                        (char*)&Bs[0][0] + g * 16);                           \
        }                                                                     \
    }
    STAGE_B(0);

    // ---- A panel in registers for full K: a[m][kidx], kidx = 0..7 ----
    bf16x8 a[2][8];
#pragma unroll
    for (int m = 0; m < 2; ++m) {
        const unsigned short* arow =
            cnb + (i0 + wrow + m * 16 + (lane & 15)) * DDIM + ((lane >> 4) << 3);
#pragma unroll
        for (int kidx = 0; kidx < 8; ++kidx)
            a[m][kidx] = *(const bf16x8*)(arow + kidx * 32);
    }

    f32x4 acc[2][4];
#pragma unroll
    for (int m = 0; m < 2; ++m)
#pragma unroll
        for (int n = 0; n < 4; ++n)
            acc[m][n] = (f32x4){0.f, 0.f, 0.f, 0.f};

#pragma unroll
    for (int kt = 0; kt < DDIM / BK; ++kt) {
        __syncthreads();   // B(kt) staged (implicit vmcnt drain before barrier)
#pragma unroll
        for (int kk = 0; kk < BK / 32; ++kk) {
            const int kslot = kk * 4 + (lane >> 4);
            bf16x8 bfr[4];
#pragma unroll
            for (int n = 0; n < 4; ++n) {
                const int row = wcol + n * 16 + (lane & 15);
                bfr[n] = *(const bf16x8*)((const char*)&Bs[0][0]
                          + row * 128 + ((kslot ^ rx) << 4));
            }
            // SWAPPED operands: D layout -> lane&15 = cn row, in-lane = tn col
#pragma unroll
            for (int m = 0; m < 2; ++m)
#pragma unroll
                for (int n = 0; n < 4; ++n)
                    acc[m][n] = __builtin_amdgcn_mfma_f32_16x16x32_bf16(
                        bfr[n], a[m][kt * 2 + kk], acc[m][n], 0, 0, 0);
        }
        __syncthreads();   // reads done before next stage overwrites
        if (kt < DDIM / BK - 1) STAGE_B(kt + 1);
    }
#undef STAGE_B

    // epilogue: exp2 + mask in registers over (n,r); shfl_xor 16,32 only.
    const float C = (1.0f / 0.07f) * 1.442695041f;   // invT * log2(e)
#pragma unroll
    for (int m = 0; m < 2; ++m) {
        const int rowm = wrow + m * 16 + (lane & 15);
        const int si = sidI[rowm];
        float ra = 0.0f, rp = 0.0f;
#pragma unroll
        for (int n = 0; n < 4; ++n) {
            const int cb = wcol + n * 16 + ((lane >> 4) << 2);
            const int4 sj4 = *(const int4*)&sidJ[cb];
            float e0 = exp2f(acc[m][n][0] * C);
            float e1 = exp2f(acc[m][n][1] * C);
            float e2 = exp2f(acc[m][n][2] * C);
            float e3 = exp2f(acc[m][n][3] * C);
            ra += e0 + e1 + e2 + e3;
            rp += (si == sj4.x) ? e0 : 0.0f;
            rp += (si == sj4.y) ? e1 : 0.0f;
            rp += (si == sj4.z) ? e2 : 0.0f;
            rp += (si == sj4.w) ? e3 : 0.0f;
        }
        ra += __shfl_xor(ra, 16, 64);
        ra += __shfl_xor(ra, 32, 64);
        rp += __shfl_xor(rp, 16, 64);
        rp += __shfl_xor(rp, 32, 64);
        if (lane < 16) {
            ps[wid & 1][wrow + m * 16 + lane][0] = ra;
            ps[wid & 1][wrow + m * 16 + lane][1] = rp;
        }
    }
    __syncthreads();
    if (t < BM) {
        const float sa = ps[0][t][0] + ps[1][t][0];
        const float sp = ps[0][t][1] + ps[1][t][1];
        pall[jb * NROWS + i0 + t] = sa;
        ppos[jb * NROWS + i0 + t] = sp;
    }
}

// ---------------------------------------------------------------------------
// Kernel 4: per-row sum over 64 j-block partials + log terms.
// ---------------------------------------------------------------------------
__global__ __launch_bounds__(256) void k_red(const float* __restrict__ pall,
                                             const float* __restrict__ ppos,
                                             float* __restrict__ contrib) {
    __shared__ float red[256];
    const int row = blockIdx.x * 256 + threadIdx.x;
    float sa = 0.0f, sp = 0.0f;
    for (int jb = 0; jb < 64; ++jb) {
        sa += pall[jb * NROWS + row];
        sp += ppos[jb * NROWS + row];
    }
    red[threadIdx.x] = logf(sa + 1e-8f) - logf(sp);
    __syncthreads();
#pragma unroll
    for (int s = 128; s > 0; s >>= 1) {
        if (threadIdx.x < s) red[threadIdx.x] += red[threadIdx.x + s];
        __syncthreads();
    }
    if (threadIdx.x == 0) contrib[blockIdx.x] = red[0];
}

// ---------------------------------------------------------------------------
// Kernel 5: fold all partials -> 4 outputs
// ---------------------------------------------------------------------------
__global__ __launch_bounds__(256) void k_final(const float* __restrict__ spat_part,
                                               const float* __restrict__ freq_part,
                                               const float* __restrict__ contrib,
                                               float* __restrict__ out) {
    __shared__ float reda[256], redb[256], redc[256];
    float a = 0.0f, b = 0.0f, c = 0.0f;
    for (int i = threadIdx.x; i < 512; i += 256) {
        a += spat_part[i];
        b += freq_part[i];
    }
    if (threadIdx.x < 32) c = contrib[threadIdx.x];
    reda[threadIdx.x] = a; redb[threadIdx.x] = b; redc[threadIdx.x] = c;
    __syncthreads();
#pragma unroll
    for (int s = 128; s > 0; s >>= 1) {
        if (threadIdx.x < s) {
            reda[threadIdx.x] += reda[threadIdx.x + s];
            redb[threadIdx.x] += redb[threadIdx.x + s];
            redc[threadIdx.x] += redc[threadIdx.x + s];
        }
        __syncthreads();
    }
    if (threadIdx.x == 0) {
        float spatial = reda[0] / (float)(NROWS * DDIM);
        float frequency = redb[0] / (float)(NROWS * NBINS);
        float contrastive = redc[0] / (float)NROWS;
        out[0] = spatial + frequency + 0.5f * contrastive;
        out[1] = spatial;
        out[2] = frequency;
        out[3] = contrastive;
    }
}

// ---------------------------------------------------------------------------
extern "C" void kernel_launch(void* const* d_in, const int* in_sizes, int n_in,
                              void* d_out, int out_size, void* d_ws, size_t ws_size,
                              hipStream_t stream) {
    const float* clean = (const float*)d_in[0];
    const float* turb  = (const float*)d_in[1];
    const int*   sids  = (const int*)d_in[2];

    char* ws = (char*)d_ws;
    unsigned short* cnb    = (unsigned short*)ws;                      // 4 MB
    unsigned short* tnb    = (unsigned short*)(ws + 4194304);          // 4 MB
    unsigned short* basisT = (unsigned short*)(ws + 8388608);          // 147 KB
    float* pall      = (float*)(ws + 8650752);                         // 2 MB
    float* ppos      = (float*)(ws + 10747904);                        // 2 MB
    float* spat_part = (float*)(ws + 12845056);                        // 2 KB
    float* freq_part = (float*)(ws + 12849152);                        // 2 KB
    float* contrib   = (float*)(ws + 12853248);                        // 128 B

    hipLaunchKernelGGL(k_basis, dim3(288), dim3(256), 0, stream, basisT);
    hipLaunchKernelGGL(k_prep, dim3(NROWS / 16), dim3(256), 0, stream,
                       clean, turb, basisT, cnb, tnb, spat_part, freq_part);
    hipLaunchKernelGGL(k_gemm, dim3((NROWS / BM) * (NROWS / BN)), dim3(256), 0, stream,
                       cnb, tnb, sids, pall, ppos);
    hipLaunchKernelGGL(k_red, dim3(NROWS / 256), dim3(256), 0, stream,
                       pall, ppos, contrib);
    hipLaunchKernelGGL(k_final, dim3(1), dim3(256), 0, stream,
                       spat_part, freq_part, contrib, (float*)d_out);
}

// Round 13
// 98.794 us; speedup vs baseline: 1.3201x; 1.3201x over previous
//
#include <hip/hip_runtime.h>

#define NROWS 8192
#define DDIM  256
#define NBINS 129

typedef float f32x4 __attribute__((ext_vector_type(4)));
typedef short bf16x8 __attribute__((ext_vector_type(8)));

__device__ __forceinline__ float wave_red(float v) {
#pragma unroll
    for (int m = 32; m; m >>= 1) v += __shfl_xor(v, m, 64);
    return v;
}

__device__ __forceinline__ unsigned bfbits(float f) {
    union { float f; unsigned u; } v; v.f = f;
    return (v.u + 0x7FFFu + ((v.u >> 16) & 1u)) >> 16;
}

__device__ __forceinline__ void gload_lds16(const void* g, void* l) {
    __builtin_amdgcn_global_load_lds((const __attribute__((address_space(1))) void*)g,
                                     (__attribute__((address_space(3))) void*)l,
                                     16, 0, 0);
}

// ---------------------------------------------------------------------------
// Kernel 1: DFT basis, transposed layout basisT[288][256] bf16.
// rows 0..128: cos(2*pi*n*k/256); rows 144..272: sin; others zero.
// ---------------------------------------------------------------------------
__global__ __launch_bounds__(256) void k_basis(unsigned short* __restrict__ basisT) {
    const int n = blockIdx.x;    // 0..287
    const int k = threadIdx.x;   // 0..255
    float v = 0.0f;
    const float step = 0.0245436926f;  // 2*pi/256
    if (n < 129)                  v = cosf(step * (float)((n * k) & 255));
    else if (n >= 144 && n < 273) v = sinf(step * (float)(((n - 144) * k) & 255));
    basisT[n * DDIM + k] = (unsigned short)bfbits(v);
}

// ---------------------------------------------------------------------------
// Kernel 2 (fused row+dft): 16 rows/block, 512 threads / 8 waves.
// Waves = {src} x {trig} x {n-half} -> 16 waves/CU at grid 512 (was 8).
//  phase 1: coalesced read (8 floats/thread/src); spatial MSE + row norms
//  phase 2: normalized bf16 write
//  phase 3: A-fragments re-read from L2-hot global (per wave)
//  phase 4: DFT MFMAs, nhalf 0 -> n=0..3, nhalf 1 -> n=4..8
//  phase 5: frequency MSE block reduce
// ---------------------------------------------------------------------------
__global__ __launch_bounds__(512) void k_prep(const float* __restrict__ clean,
                                              const float* __restrict__ turb,
                                              const unsigned short* __restrict__ basisT,
                                              unsigned short* __restrict__ cnb,
                                              unsigned short* __restrict__ tnb,
                                              float* __restrict__ spat_part,
                                              float* __restrict__ freq_part) {
    __shared__ float xch[2][2][16][132];   // [src][trig][row][bin] cr/ci  (33 KB)
    __shared__ float invn[16][2];
    __shared__ float sp8[8], rbuf[8];

    const int t    = threadIdx.x;          // 0..511
    const int w    = t >> 6;               // 0..7
    const int lane = t & 63;
    const int rb   = blockIdx.x * 16;

    // ---- phase 1: coalesced load (row = t>>5, 8-float chunk = t&31) ----
    const int row = t >> 5;
    const int c8  = (t & 31) * 8;
    const float* pc = clean + (rb + row) * DDIM + c8;
    const float* pt = turb  + (rb + row) * DDIM + c8;
    const float4 xc0 = ((const float4*)pc)[0], xc1 = ((const float4*)pc)[1];
    const float4 xt0 = ((const float4*)pt)[0], xt1 = ((const float4*)pt)[1];

    float dsq = (xc0.x - xt0.x) * (xc0.x - xt0.x) + (xc0.y - xt0.y) * (xc0.y - xt0.y)
              + (xc0.z - xt0.z) * (xc0.z - xt0.z) + (xc0.w - xt0.w) * (xc0.w - xt0.w)
              + (xc1.x - xt1.x) * (xc1.x - xt1.x) + (xc1.y - xt1.y) * (xc1.y - xt1.y)
              + (xc1.z - xt1.z) * (xc1.z - xt1.z) + (xc1.w - xt1.w) * (xc1.w - xt1.w);
    float nsc = xc0.x * xc0.x + xc0.y * xc0.y + xc0.z * xc0.z + xc0.w * xc0.w
              + xc1.x * xc1.x + xc1.y * xc1.y + xc1.z * xc1.z + xc1.w * xc1.w;
    float nst = xt0.x * xt0.x + xt0.y * xt0.y + xt0.z * xt0.z + xt0.w * xt0.w
              + xt1.x * xt1.x + xt1.y * xt1.y + xt1.z * xt1.z + xt1.w * xt1.w;

    // norm reduce over the 32 threads of this row (contained in one wave)
#pragma unroll
    for (int m = 1; m < 32; m <<= 1) {
        nsc += __shfl_xor(nsc, m, 64);
        nst += __shfl_xor(nst, m, 64);
    }
    if ((t & 31) == 0) {
        invn[row][0] = 1.0f / fmaxf(sqrtf(nsc), 1e-12f);
        invn[row][1] = 1.0f / fmaxf(sqrtf(nst), 1e-12f);
    }
    dsq = wave_red(dsq);
    if (lane == 0) sp8[w] = dsq;
    __syncthreads();

    // ---- phase 2: normalized bf16 writes (16B coalesced stores) ----
    {
        const float ic = invn[row][0], it = invn[row][1];
        bf16x8 oc, ot;
        oc[0] = (short)bfbits(xc0.x * ic); oc[1] = (short)bfbits(xc0.y * ic);
        oc[2] = (short)bfbits(xc0.z * ic); oc[3] = (short)bfbits(xc0.w * ic);
        oc[4] = (short)bfbits(xc1.x * ic); oc[5] = (short)bfbits(xc1.y * ic);
        oc[6] = (short)bfbits(xc1.z * ic); oc[7] = (short)bfbits(xc1.w * ic);
        ot[0] = (short)bfbits(xt0.x * it); ot[1] = (short)bfbits(xt0.y * it);
        ot[2] = (short)bfbits(xt0.z * it); ot[3] = (short)bfbits(xt0.w * it);
        ot[4] = (short)bfbits(xt1.x * it); ot[5] = (short)bfbits(xt1.y * it);
        ot[6] = (short)bfbits(xt1.z * it); ot[7] = (short)bfbits(xt1.w * it);
        *(bf16x8*)(cnb + (rb + row) * DDIM + c8) = oc;
        *(bf16x8*)(tnb + (rb + row) * DDIM + c8) = ot;
    }

    // ---- phase 3: A-fragments from L2-hot global (per wave) ----
    const int srcw = w & 1;                 // 0 clean, 1 turb
    const int trig = (w >> 1) & 1;          // 0 cos, 1 sin
    const int nh   = w >> 2;                // n-half
    bf16x8 a[8];
    {
        const float* src = srcw ? turb : clean;
        const float* rowp = src + (rb + (lane & 15)) * DDIM + ((lane >> 4) << 3);
#pragma unroll
        for (int kk = 0; kk < 8; ++kk) {
            const float4 lo = *(const float4*)(rowp + kk * 32);
            const float4 hi = *(const float4*)(rowp + kk * 32 + 4);
            bf16x8 tv;
            tv[0] = (short)bfbits(lo.x); tv[1] = (short)bfbits(lo.y);
            tv[2] = (short)bfbits(lo.z); tv[3] = (short)bfbits(lo.w);
            tv[4] = (short)bfbits(hi.x); tv[5] = (short)bfbits(hi.y);
            tv[6] = (short)bfbits(hi.z); tv[7] = (short)bfbits(hi.w);
            a[kk] = tv;
        }
    }

    // ---- phase 4: DFT MFMAs (nh=0: n=0..3, nh=1: n=4..8) ----
    const unsigned short* bbase = basisT + (trig * 144 + (lane & 15)) * DDIM
                                + ((lane >> 4) << 3);
    const int lrow = (lane >> 4) << 2;
    const int nlo = nh ? 4 : 0;
    const int nhi = nh ? 9 : 4;
#pragma unroll 1
    for (int n = nlo; n < nhi; ++n) {
        f32x4 acc = (f32x4){0.f, 0.f, 0.f, 0.f};
#pragma unroll
        for (int kk = 0; kk < 8; ++kk) {
            bf16x8 b = *(const bf16x8*)(bbase + n * 16 * DDIM + kk * 32);
            acc = __builtin_amdgcn_mfma_f32_16x16x32_bf16(a[kk], b, acc, 0, 0, 0);
        }
        const int bin = n * 16 + (lane & 15);
        if (bin <= 128) {   // GUARD: n=8 covers bins 128..143; only 128 is real.
#pragma unroll
            for (int rr = 0; rr < 4; ++rr)
                xch[srcw][trig][lrow + rr][bin] = acc[rr];
        }
    }
    __syncthreads();

    // ---- phase 5: block reduce (|fft_c| - |fft_t|)^2, 16 rows x 129 bins ----
    {
        const int rr = t >> 5;
        float s = 0.0f;
        for (int b = (t & 31); b < NBINS; b += 32) {
            const float crc = xch[0][0][rr][b], cic = xch[0][1][rr][b];
            const float crt = xch[1][0][rr][b], cit = xch[1][1][rr][b];
            const float d = sqrtf(crc * crc + cic * cic)
                          - sqrtf(crt * crt + cit * cit);
            s += d * d;
        }
        s = wave_red(s);
        if (lane == 0) rbuf[w] = s;
    }
    __syncthreads();
    if (t == 0) {
        freq_part[blockIdx.x] = rbuf[0] + rbuf[1] + rbuf[2] + rbuf[3]
                              + rbuf[4] + rbuf[5] + rbuf[6] + rbuf[7];
        spat_part[blockIdx.x] = sp8[0] + sp8[1] + sp8[2] + sp8[3]
                              + sp8[4] + sp8[5] + sp8[6] + sp8[7];
    }
}

// ---------------------------------------------------------------------------
// Kernel 3: 128x128 bf16 MFMA GEMM — EXACT r10 winner (53.5 us measured).
// Swapped-operand MFMA epilogue, supertile XCD swizzle, swizzled staging,
// single-buffer LDS, plain launch bounds.
// ---------------------------------------------------------------------------
#define BM 128
#define BN 128
#define BK 64

__global__ __launch_bounds__(256) void k_gemm(const unsigned short* __restrict__ cnb,
                                              const unsigned short* __restrict__ tnb,
                                              const int* __restrict__ sid,
                                              float* __restrict__ pall,
                                              float* __restrict__ ppos) {
    __shared__ unsigned short As[BM][BK];
    __shared__ unsigned short Bs[BN][BK];
    __shared__ float ps[2][BM][2];          // [colhalf][row][all|pos]
    __shared__ int sidI[BM], sidJ[BN];

    // Supertile XCD swizzle: bijective (4096%8==0), ~1 MB working set/XCD.
    const int bid = blockIdx.x;
    const int xcd = bid & 7;
    const int q   = bid >> 3;            // 0..511
    const int grp = q >> 6;              // jb supertile group 0..7
    const int r   = q & 63;
    const int ib  = xcd * 8 + (r >> 3);
    const int jb  = grp * 8 + (r & 7);
    const int i0  = ib * BM;
    const int j0  = jb * BN;

    const int t = threadIdx.x;
    if (t < 128) sidI[t] = sid[i0 + t];
    else         sidJ[t - 128] = sid[j0 + t - 128];

    const int wid  = t >> 6;
    const int lane = t & 63;
    const int wrow = (wid >> 1) * 64;
    const int wcol = (wid & 1) * 64;
    const int rx   = lane & 7;

    f32x4 acc[4][4];
#pragma unroll
    for (int m = 0; m < 4; ++m)
#pragma unroll
        for (int n = 0; n < 4; ++n)
            acc[m][n] = (f32x4){0.f, 0.f, 0.f, 0.f};

    for (int kt = 0; kt < DDIM / BK; ++kt) {
        // stage: linear LDS dest, inverse-swizzled global source
#pragma unroll
        for (int it = 0; it < 4; ++it) {
            const int g  = it * 256 + t;          // 16B granule 0..1023
            const int rr = g >> 3;
            const int sl = g & 7;
            const int sc = ((sl ^ (rr & 7)) << 3);
            gload_lds16(cnb + (i0 + rr) * DDIM + kt * BK + sc,
                        (char*)&As[0][0] + g * 16);
            gload_lds16(tnb + (j0 + rr) * DDIM + kt * BK + sc,
                        (char*)&Bs[0][0] + g * 16);
        }
        __syncthreads();   // drains vmcnt before reads
#pragma unroll
        for (int kk = 0; kk < BK / 32; ++kk) {
            const int kslot = kk * 4 + (lane >> 4);
            bf16x8 af[4], bfr[4];
#pragma unroll
            for (int m = 0; m < 4; ++m) {
                const int row = wrow + m * 16 + (lane & 15);
                af[m] = *(const bf16x8*)((const char*)&As[0][0]
                          + row * 128 + ((kslot ^ rx) << 4));
            }
#pragma unroll
            for (int n = 0; n < 4; ++n) {
                const int row = wcol + n * 16 + (lane & 15);
                bfr[n] = *(const bf16x8*)((const char*)&Bs[0][0]
                          + row * 128 + ((kslot ^ rx) << 4));
            }
            // SWAPPED: D layout -> lane&15 = cn row, in-lane r = tn col.
#pragma unroll
            for (int m = 0; m < 4; ++m)
#pragma unroll
                for (int n = 0; n < 4; ++n)
                    acc[m][n] = __builtin_amdgcn_mfma_f32_16x16x32_bf16(
                        bfr[n], af[m], acc[m][n], 0, 0, 0);
        }
        __syncthreads();   // all reads done before next stage overwrites
    }

    // epilogue: exp2 + mask in registers over (n,r); shfl_xor 16,32 only.
    const float C = (1.0f / 0.07f) * 1.442695041f;   // invT * log2(e)
#pragma unroll
    for (int m = 0; m < 4; ++m) {
        const int rowm = wrow + m * 16 + (lane & 15);   // this lane's row
        const int si = sidI[rowm];
        float ra = 0.0f, rp = 0.0f;
#pragma unroll
        for (int n = 0; n < 4; ++n) {
            const int cb = wcol + n * 16 + ((lane >> 4) << 2);
            const int4 sj4 = *(const int4*)&sidJ[cb];
            float e0 = exp2f(acc[m][n][0] * C);
            float e1 = exp2f(acc[m][n][1] * C);
            float e2 = exp2f(acc[m][n][2] * C);
            float e3 = exp2f(acc[m][n][3] * C);
            ra += e0 + e1 + e2 + e3;
            rp += (si == sj4.x) ? e0 : 0.0f;
            rp += (si == sj4.y) ? e1 : 0.0f;
            rp += (si == sj4.z) ? e2 : 0.0f;
            rp += (si == sj4.w) ? e3 : 0.0f;
        }
        ra += __shfl_xor(ra, 16, 64);
        ra += __shfl_xor(ra, 32, 64);
        rp += __shfl_xor(rp, 16, 64);
        rp += __shfl_xor(rp, 32, 64);
        if (lane < 16) {
            ps[wid & 1][wrow + m * 16 + lane][0] = ra;
            ps[wid & 1][wrow + m * 16 + lane][1] = rp;
        }
    }
    __syncthreads();
    if (t < BM) {
        const float sa = ps[0][t][0] + ps[1][t][0];
        const float sp = ps[0][t][1] + ps[1][t][1];
        pall[jb * NROWS + i0 + t] = sa;
        ppos[jb * NROWS + i0 + t] = sp;
    }
}

// ---------------------------------------------------------------------------
// Kernel 4: per-row sum over 64 j-block partials + log terms.
// ---------------------------------------------------------------------------
__global__ __launch_bounds__(256) void k_red(const float* __restrict__ pall,
                                             const float* __restrict__ ppos,
                                             float* __restrict__ contrib) {
    __shared__ float red[256];
    const int row = blockIdx.x * 256 + threadIdx.x;
    float sa = 0.0f, sp = 0.0f;
    for (int jb = 0; jb < 64; ++jb) {
        sa += pall[jb * NROWS + row];
        sp += ppos[jb * NROWS + row];
    }
    red[threadIdx.x] = logf(sa + 1e-8f) - logf(sp);
    __syncthreads();
#pragma unroll
    for (int s = 128; s > 0; s >>= 1) {
        if (threadIdx.x < s) red[threadIdx.x] += red[threadIdx.x + s];
        __syncthreads();
    }
    if (threadIdx.x == 0) contrib[blockIdx.x] = red[0];
}

// ---------------------------------------------------------------------------
// Kernel 5: fold all partials -> 4 outputs
// ---------------------------------------------------------------------------
__global__ __launch_bounds__(256) void k_final(const float* __restrict__ spat_part,
                                               const float* __restrict__ freq_part,
                                               const float* __restrict__ contrib,
                                               float* __restrict__ out) {
    __shared__ float reda[256], redb[256], redc[256];
    float a = 0.0f, b = 0.0f, c = 0.0f;
    for (int i = threadIdx.x; i < 512; i += 256) {
        a += spat_part[i];
        b += freq_part[i];
    }
    if (threadIdx.x < 32) c = contrib[threadIdx.x];
    reda[threadIdx.x] = a; redb[threadIdx.x] = b; redc[threadIdx.x] = c;
    __syncthreads();
#pragma unroll
    for (int s = 128; s > 0; s >>= 1) {
        if (threadIdx.x < s) {
            reda[threadIdx.x] += reda[threadIdx.x + s];
            redb[threadIdx.x] += redb[threadIdx.x + s];
            redc[threadIdx.x] += redc[threadIdx.x + s];
        }
        __syncthreads();
    }
    if (threadIdx.x == 0) {
        float spatial = reda[0] / (float)(NROWS * DDIM);
        float frequency = redb[0] / (float)(NROWS * NBINS);
        float contrastive = redc[0] / (float)NROWS;
        out[0] = spatial + frequency + 0.5f * contrastive;
        out[1] = spatial;
        out[2] = frequency;
        out[3] = contrastive;
    }
}

// ---------------------------------------------------------------------------
extern "C" void kernel_launch(void* const* d_in, const int* in_sizes, int n_in,
                              void* d_out, int out_size, void* d_ws, size_t ws_size,
                              hipStream_t stream) {
    const float* clean = (const float*)d_in[0];
    const float* turb  = (const float*)d_in[1];
    const int*   sids  = (const int*)d_in[2];

    char* ws = (char*)d_ws;
    unsigned short* cnb    = (unsigned short*)ws;                      // 4 MB
    unsigned short* tnb    = (unsigned short*)(ws + 4194304);          // 4 MB
    unsigned short* basisT = (unsigned short*)(ws + 8388608);          // 147 KB
    float* pall      = (float*)(ws + 8650752);                         // 2 MB
    float* ppos      = (float*)(ws + 10747904);                        // 2 MB
    float* spat_part = (float*)(ws + 12845056);                        // 2 KB
    float* freq_part = (float*)(ws + 12849152);                        // 2 KB
    float* contrib   = (float*)(ws + 12853248);                        // 128 B

    hipLaunchKernelGGL(k_basis, dim3(288), dim3(256), 0, stream, basisT);
    hipLaunchKernelGGL(k_prep, dim3(NROWS / 16), dim3(512), 0, stream,
                       clean, turb, basisT, cnb, tnb, spat_part, freq_part);
    hipLaunchKernelGGL(k_gemm, dim3(4096), dim3(256), 0, stream,
                       cnb, tnb, sids, pall, ppos);
    hipLaunchKernelGGL(k_red, dim3(NROWS / 256), dim3(256), 0, stream,
                       pall, ppos, contrib);
    hipLaunchKernelGGL(k_final, dim3(1), dim3(256), 0, stream,
                       spat_part, freq_part, contrib, (float*)d_out);
}

// Round 14
// 95.605 us; speedup vs baseline: 1.3641x; 1.0334x over previous
//
#include <hip/hip_runtime.h>

#define NROWS 8192
#define DDIM  256
#define NBINS 129

typedef float f32x4 __attribute__((ext_vector_type(4)));
typedef short bf16x8 __attribute__((ext_vector_type(8)));

__device__ __forceinline__ float wave_red(float v) {
#pragma unroll
    for (int m = 32; m; m >>= 1) v += __shfl_xor(v, m, 64);
    return v;
}

__device__ __forceinline__ unsigned bfbits(float f) {
    union { float f; unsigned u; } v; v.f = f;
    return (v.u + 0x7FFFu + ((v.u >> 16) & 1u)) >> 16;
}

__device__ __forceinline__ void gload_lds16(const void* g, void* l) {
    __builtin_amdgcn_global_load_lds((const __attribute__((address_space(1))) void*)g,
                                     (__attribute__((address_space(3))) void*)l,
                                     16, 0, 0);
}

// ---------------------------------------------------------------------------
// Kernel 1: DFT basis, transposed layout basisT[288][256] bf16.
// rows 0..128: cos(2*pi*n*k/256); rows 144..272: sin; others zero.
// ---------------------------------------------------------------------------
__global__ __launch_bounds__(256) void k_basis(unsigned short* __restrict__ basisT) {
    const int n = blockIdx.x;    // 0..287
    const int k = threadIdx.x;   // 0..255
    float v = 0.0f;
    const float step = 0.0245436926f;  // 2*pi/256
    if (n < 129)                  v = cosf(step * (float)((n * k) & 255));
    else if (n >= 144 && n < 273) v = sinf(step * (float)(((n - 144) * k) & 255));
    basisT[n * DDIM + k] = (unsigned short)bfbits(v);
}

// ---------------------------------------------------------------------------
// Kernel 2 (fused row+dft): 16 rows/block, 256 threads — r10-measured-best.
// ---------------------------------------------------------------------------
__global__ __launch_bounds__(256) void k_prep(const float* __restrict__ clean,
                                              const float* __restrict__ turb,
                                              const unsigned short* __restrict__ basisT,
                                              unsigned short* __restrict__ cnb,
                                              unsigned short* __restrict__ tnb,
                                              float* __restrict__ spat_part,
                                              float* __restrict__ freq_part) {
    __shared__ float xch[2][2][16][132];   // [src][trig][row][bin] cr/ci  (33 KB)
    __shared__ float invn[16][2];
    __shared__ float sp4[4], rbuf[4];

    const int t    = threadIdx.x;
    const int w    = t >> 6;
    const int lane = t & 63;
    const int rb   = blockIdx.x * 16;

    // ---- phase 1: coalesced load; per-row norms; spatial partial ----
    float4 xc4[4], xt4[4];
    float dsq = 0.0f;
#pragma unroll
    for (int q = 0; q < 4; ++q) {
        const int row = q * 4 + w;           // wave w owns row q*4+w
        const float* pc = clean + (rb + row) * DDIM + lane * 4;
        const float* pt = turb  + (rb + row) * DDIM + lane * 4;
        xc4[q] = *(const float4*)pc;
        xt4[q] = *(const float4*)pt;
        const float4 a = xc4[q], b = xt4[q];
        dsq += (a.x - b.x) * (a.x - b.x) + (a.y - b.y) * (a.y - b.y)
             + (a.z - b.z) * (a.z - b.z) + (a.w - b.w) * (a.w - b.w);
        float nsc = a.x * a.x + a.y * a.y + a.z * a.z + a.w * a.w;
        float nst = b.x * b.x + b.y * b.y + b.z * b.z + b.w * b.w;
        nsc = wave_red(nsc);
        nst = wave_red(nst);
        if (lane == 0) {
            invn[row][0] = 1.0f / fmaxf(sqrtf(nsc), 1e-12f);
            invn[row][1] = 1.0f / fmaxf(sqrtf(nst), 1e-12f);
        }
    }
    dsq = wave_red(dsq);
    if (lane == 0) sp4[w] = dsq;
    __syncthreads();

    // ---- phase 2: normalized bf16 writes (8B coalesced stores) ----
#pragma unroll
    for (int q = 0; q < 4; ++q) {
        const int row = q * 4 + w;
        const float ic = invn[row][0], it = invn[row][1];
        const float4 a = xc4[q], b = xt4[q];
        uint2 pc, pt;
        pc.x = bfbits(a.x * ic) | (bfbits(a.y * ic) << 16);
        pc.y = bfbits(a.z * ic) | (bfbits(a.w * ic) << 16);
        pt.x = bfbits(b.x * it) | (bfbits(b.y * it) << 16);
        pt.y = bfbits(b.z * it) | (bfbits(b.w * it) << 16);
        *(uint2*)(cnb + (rb + row) * DDIM + lane * 4) = pc;
        *(uint2*)(tnb + (rb + row) * DDIM + lane * 4) = pt;
    }

    // ---- phase 3: A-fragments from L2-hot global ----
    const int srcw = w & 1;         // 0 clean, 1 turb
    const int trig = w >> 1;        // 0 cos, 1 sin
    bf16x8 a[8];
    {
        const float* src = srcw ? turb : clean;
        const float* rowp = src + (rb + (lane & 15)) * DDIM + ((lane >> 4) << 3);
#pragma unroll
        for (int kk = 0; kk < 8; ++kk) {
            const float4 lo = *(const float4*)(rowp + kk * 32);
            const float4 hi = *(const float4*)(rowp + kk * 32 + 4);
            bf16x8 tv;
            tv[0] = (short)bfbits(lo.x); tv[1] = (short)bfbits(lo.y);
            tv[2] = (short)bfbits(lo.z); tv[3] = (short)bfbits(lo.w);
            tv[4] = (short)bfbits(hi.x); tv[5] = (short)bfbits(hi.y);
            tv[6] = (short)bfbits(hi.z); tv[7] = (short)bfbits(hi.w);
            a[kk] = tv;
        }
    }

    // ---- phase 4: DFT MFMAs ----
    const unsigned short* bbase = basisT + (trig * 144 + (lane & 15)) * DDIM
                                + ((lane >> 4) << 3);
    const int lrow = (lane >> 4) << 2;
#pragma unroll 1
    for (int n = 0; n < 9; ++n) {
        f32x4 acc = (f32x4){0.f, 0.f, 0.f, 0.f};
#pragma unroll
        for (int kk = 0; kk < 8; ++kk) {
            bf16x8 b = *(const bf16x8*)(bbase + n * 16 * DDIM + kk * 32);
            acc = __builtin_amdgcn_mfma_f32_16x16x32_bf16(a[kk], b, acc, 0, 0, 0);
        }
        const int bin = n * 16 + (lane & 15);
        if (bin <= 128) {   // GUARD: n=8 covers bins 128..143; only 128 is real.
#pragma unroll
            for (int rr = 0; rr < 4; ++rr)
                xch[srcw][trig][lrow + rr][bin] = acc[rr];
        }
    }
    __syncthreads();

    // block reduce of (|fft_c| - |fft_t|)^2 over 16 rows x 129 bins
    {
        const int rr = t >> 4;
        float s = 0.0f;
        for (int b = (t & 15); b < NBINS; b += 16) {
            const float crc = xch[0][0][rr][b], cic = xch[0][1][rr][b];
            const float crt = xch[1][0][rr][b], cit = xch[1][1][rr][b];
            const float d = sqrtf(crc * crc + cic * cic)
                          - sqrtf(crt * crt + cit * cit);
            s += d * d;
        }
        s = wave_red(s);
        if (lane == 0) rbuf[w] = s;
    }
    __syncthreads();
    if (t == 0) {
        freq_part[blockIdx.x] = rbuf[0] + rbuf[1] + rbuf[2] + rbuf[3];
        spat_part[blockIdx.x] = sp4[0] + sp4[1] + sp4[2] + sp4[3];
    }
}

// ---------------------------------------------------------------------------
// Kernel 3: 128x128 bf16 MFMA GEMM, T3-minimum 2-phase double-buffer with
// BK=32 (LDS stays ~35 KB): STAGE(next) issued BEFORE compute(cur), single
// barrier per kt (drain lands AFTER compute -> staging latency hidden).
// 4-slot XOR swizzle ((row>>1)&3) keeps fragment reads 2-way/bank-free.
// Swapped-operand MFMA epilogue + supertile XCD swizzle (both validated).
// ---------------------------------------------------------------------------
#define BM 128
#define BN 128
#define BK 32

__global__ __launch_bounds__(256) void k_gemm(const unsigned short* __restrict__ cnb,
                                              const unsigned short* __restrict__ tnb,
                                              const int* __restrict__ sid,
                                              float* __restrict__ pall,
                                              float* __restrict__ ppos) {
    __shared__ unsigned short As[2][BM][BK];   // 16 KB
    __shared__ unsigned short Bs[2][BN][BK];   // 16 KB
    __shared__ float ps[2][BM][2];             // [colhalf][row][all|pos]
    __shared__ int sidI[BM], sidJ[BN];

    // Supertile XCD swizzle: bijective (4096%8==0), ~1 MB working set/XCD.
    const int bid = blockIdx.x;
    const int xcd = bid & 7;
    const int q   = bid >> 3;            // 0..511
    const int grp = q >> 6;              // jb supertile group 0..7
    const int r   = q & 63;
    const int ib  = xcd * 8 + (r >> 3);
    const int jb  = grp * 8 + (r & 7);
    const int i0  = ib * BM;
    const int j0  = jb * BN;

    const int t = threadIdx.x;
    if (t < 128) sidI[t] = sid[i0 + t];
    else         sidJ[t - 128] = sid[j0 + t - 128];

    const int wid  = t >> 6;
    const int lane = t & 63;
    const int wrow = (wid >> 1) * 64;
    const int wcol = (wid & 1) * 64;
    const int rx2  = ((lane & 15) >> 1) & 3;   // read-side XOR ((row>>1)&3)

    f32x4 acc[4][4];
#pragma unroll
    for (int m = 0; m < 4; ++m)
#pragma unroll
        for (int n = 0; n < 4; ++n)
            acc[m][n] = (f32x4){0.f, 0.f, 0.f, 0.f};

    // stage one 128x32 tile pair: 512 granules each (2/thread).
    // dest slot sl holds source slot sl^((row>>1)&3)  (16B granules, 4/row)
#define STAGE(buf, kt)                                                        \
    {                                                                         \
        _Pragma("unroll")                                                     \
        for (int it = 0; it < 2; ++it) {                                      \
            const int g  = it * 256 + t;          /* granule 0..511 */        \
            const int rr = g >> 2;                /* row 0..127 */            \
            const int sl = g & 3;                                             \
            const int sc = ((sl ^ ((rr >> 1) & 3)) << 3);                     \
            gload_lds16(cnb + (i0 + rr) * DDIM + (kt) * BK + sc,              \
                        (char*)&As[buf][0][0] + g * 16);                      \
            gload_lds16(tnb + (j0 + rr) * DDIM + (kt) * BK + sc,              \
                        (char*)&Bs[buf][0][0] + g * 16);                      \
        }                                                                     \
    }

    int cur = 0;
    STAGE(0, 0);
    __syncthreads();                    // tile 0 staged (vmcnt drained)

#pragma unroll
    for (int kt = 0; kt < DDIM / BK; ++kt) {
        if (kt < DDIM / BK - 1) STAGE(cur ^ 1, kt + 1);   // prefetch, no wait
        const int kslot = lane >> 4;    // 16B K-chunk 0..3
        bf16x8 af[4], bfr[4];
#pragma unroll
        for (int m = 0; m < 4; ++m) {
            const int row = wrow + m * 16 + (lane & 15);
            af[m] = *(const bf16x8*)((const char*)&As[cur][0][0]
                      + row * 64 + ((kslot ^ rx2) << 4));
        }
#pragma unroll
        for (int n = 0; n < 4; ++n) {
            const int row = wcol + n * 16 + (lane & 15);
            bfr[n] = *(const bf16x8*)((const char*)&Bs[cur][0][0]
                      + row * 64 + ((kslot ^ rx2) << 4));
        }
        // SWAPPED: D layout -> lane&15 = cn row, in-lane r = tn col.
#pragma unroll
        for (int m = 0; m < 4; ++m)
#pragma unroll
            for (int n = 0; n < 4; ++n)
                acc[m][n] = __builtin_amdgcn_mfma_f32_16x16x32_bf16(
                    bfr[n], af[m], acc[m][n], 0, 0, 0);
        __syncthreads();   // drain prefetch (post-compute) + buffer handoff
        cur ^= 1;
    }
#undef STAGE

    // epilogue: exp2 + mask in registers over (n,r); shfl_xor 16,32 only.
    const float C = (1.0f / 0.07f) * 1.442695041f;   // invT * log2(e)
#pragma unroll
    for (int m = 0; m < 4; ++m) {
        const int rowm = wrow + m * 16 + (lane & 15);   // this lane's row
        const int si = sidI[rowm];
        float ra = 0.0f, rp = 0.0f;
#pragma unroll
        for (int n = 0; n < 4; ++n) {
            const int cb = wcol + n * 16 + ((lane >> 4) << 2);
            const int4 sj4 = *(const int4*)&sidJ[cb];
            float e0 = exp2f(acc[m][n][0] * C);
            float e1 = exp2f(acc[m][n][1] * C);
            float e2 = exp2f(acc[m][n][2] * C);
            float e3 = exp2f(acc[m][n][3] * C);
            ra += e0 + e1 + e2 + e3;
            rp += (si == sj4.x) ? e0 : 0.0f;
            rp += (si == sj4.y) ? e1 : 0.0f;
            rp += (si == sj4.z) ? e2 : 0.0f;
            rp += (si == sj4.w) ? e3 : 0.0f;
        }
        ra += __shfl_xor(ra, 16, 64);
        ra += __shfl_xor(ra, 32, 64);
        rp += __shfl_xor(rp, 16, 64);
        rp += __shfl_xor(rp, 32, 64);
        if (lane < 16) {
            ps[wid & 1][wrow + m * 16 + lane][0] = ra;
            ps[wid & 1][wrow + m * 16 + lane][1] = rp;
        }
    }
    __syncthreads();
    if (t < BM) {
        const float sa = ps[0][t][0] + ps[1][t][0];
        const float sp = ps[0][t][1] + ps[1][t][1];
        pall[jb * NROWS + i0 + t] = sa;
        ppos[jb * NROWS + i0 + t] = sp;
    }
}

// ---------------------------------------------------------------------------
// Kernel 4: per-row sum over 64 j-block partials + log terms.
// ---------------------------------------------------------------------------
__global__ __launch_bounds__(256) void k_red(const float* __restrict__ pall,
                                             const float* __restrict__ ppos,
                                             float* __restrict__ contrib) {
    __shared__ float red[256];
    const int row = blockIdx.x * 256 + threadIdx.x;
    float sa = 0.0f, sp = 0.0f;
    for (int jb = 0; jb < 64; ++jb) {
        sa += pall[jb * NROWS + row];
        sp += ppos[jb * NROWS + row];
    }
    red[threadIdx.x] = logf(sa + 1e-8f) - logf(sp);
    __syncthreads();
#pragma unroll
    for (int s = 128; s > 0; s >>= 1) {
        if (threadIdx.x < s) red[threadIdx.x] += red[threadIdx.x + s];
        __syncthreads();
    }
    if (threadIdx.x == 0) contrib[blockIdx.x] = red[0];
}

// ---------------------------------------------------------------------------
// Kernel 5: fold all partials -> 4 outputs
// ---------------------------------------------------------------------------
__global__ __launch_bounds__(256) void k_final(const float* __restrict__ spat_part,
                                               const float* __restrict__ freq_part,
                                               const float* __restrict__ contrib,
                                               float* __restrict__ out) {
    __shared__ float reda[256], redb[256], redc[256];
    float a = 0.0f, b = 0.0f, c = 0.0f;
    for (int i = threadIdx.x; i < 512; i += 256) {
        a += spat_part[i];
        b += freq_part[i];
    }
    if (threadIdx.x < 32) c = contrib[threadIdx.x];
    reda[threadIdx.x] = a; redb[threadIdx.x] = b; redc[threadIdx.x] = c;
    __syncthreads();
#pragma unroll
    for (int s = 128; s > 0; s >>= 1) {
        if (threadIdx.x < s) {
            reda[threadIdx.x] += reda[threadIdx.x + s];
            redb[threadIdx.x] += redb[threadIdx.x + s];
            redc[threadIdx.x] += redc[threadIdx.x + s];
        }
        __syncthreads();
    }
    if (threadIdx.x == 0) {
        float spatial = reda[0] / (float)(NROWS * DDIM);
        float frequency = redb[0] / (float)(NROWS * NBINS);
        float contrastive = redc[0] / (float)NROWS;
        out[0] = spatial + frequency + 0.5f * contrastive;
        out[1] = spatial;
        out[2] = frequency;
        out[3] = contrastive;
    }
}

// ---------------------------------------------------------------------------
extern "C" void kernel_launch(void* const* d_in, const int* in_sizes, int n_in,
                              void* d_out, int out_size, void* d_ws, size_t ws_size,
                              hipStream_t stream) {
    const float* clean = (const float*)d_in[0];
    const float* turb  = (const float*)d_in[1];
    const int*   sids  = (const int*)d_in[2];

    char* ws = (char*)d_ws;
    unsigned short* cnb    = (unsigned short*)ws;                      // 4 MB
    unsigned short* tnb    = (unsigned short*)(ws + 4194304);          // 4 MB
    unsigned short* basisT = (unsigned short*)(ws + 8388608);          // 147 KB
    float* pall      = (float*)(ws + 8650752);                         // 2 MB
    float* ppos      = (float*)(ws + 10747904);                        // 2 MB
    float* spat_part = (float*)(ws + 12845056);                        // 2 KB
    float* freq_part = (float*)(ws + 12849152);                        // 2 KB
    float* contrib   = (float*)(ws + 12853248);                        // 128 B

    hipLaunchKernelGGL(k_basis, dim3(288), dim3(256), 0, stream, basisT);
    hipLaunchKernelGGL(k_prep, dim3(NROWS / 16), dim3(256), 0, stream,
                       clean, turb, basisT, cnb, tnb, spat_part, freq_part);
    hipLaunchKernelGGL(k_gemm, dim3(4096), dim3(256), 0, stream,
                       cnb, tnb, sids, pall, ppos);
    hipLaunchKernelGGL(k_red, dim3(NROWS / 256), dim3(256), 0, stream,
                       pall, ppos, contrib);
    hipLaunchKernelGGL(k_final, dim3(1), dim3(256), 0, stream,
                       spat_part, freq_part, contrib, (float*)d_out);
}

// Round 15
// 94.289 us; speedup vs baseline: 1.3832x; 1.0140x over previous
//
#include <hip/hip_runtime.h>

#define NROWS 8192
#define DDIM  256
#define NBINS 129

typedef float f32x4 __attribute__((ext_vector_type(4)));
typedef short bf16x8 __attribute__((ext_vector_type(8)));

__device__ __forceinline__ float wave_red(float v) {
#pragma unroll
    for (int m = 32; m; m >>= 1) v += __shfl_xor(v, m, 64);
    return v;
}

__device__ __forceinline__ unsigned bfbits(float f) {
    union { float f; unsigned u; } v; v.f = f;
    return (v.u + 0x7FFFu + ((v.u >> 16) & 1u)) >> 16;
}

__device__ __forceinline__ void gload_lds16(const void* g, void* l) {
    __builtin_amdgcn_global_load_lds((const __attribute__((address_space(1))) void*)g,
                                     (__attribute__((address_space(3))) void*)l,
                                     16, 0, 0);
}

// ---------------------------------------------------------------------------
// Kernel 1: DFT basis, transposed layout basisT[288][256] bf16.
// rows 0..128: cos(2*pi*n*k/256); rows 144..272: sin; others zero.
// ---------------------------------------------------------------------------
__global__ __launch_bounds__(256) void k_basis(unsigned short* __restrict__ basisT) {
    const int n = blockIdx.x;    // 0..287
    const int k = threadIdx.x;   // 0..255
    float v = 0.0f;
    const float step = 0.0245436926f;  // 2*pi/256
    if (n < 129)                  v = cosf(step * (float)((n * k) & 255));
    else if (n >= 144 && n < 273) v = sinf(step * (float)(((n - 144) * k) & 255));
    basisT[n * DDIM + k] = (unsigned short)bfbits(v);
}

// ---------------------------------------------------------------------------
// Kernel 2 (fused row+dft): 16 rows/block, SINGLE global pass.
//  phase 1: coalesced fp32 read; spatial MSE + row norms; RAW bf16 -> LDS
//  phase 2: normalized bf16 write (global, for k_gemm)
//  phase 3: A-fragments read from LDS (was: second global pass)
//  phase 4: DFT via MFMA vs basisT; phase 5: frequency MSE reduce
// LDS = 33 (xch) + 16.5 (xraw, +8-elem pad: stride 528 B = 4-bank offset,
// frag reads 2-way free) ~ 51 KB -> 3 blocks/CU.
// ---------------------------------------------------------------------------
__global__ __launch_bounds__(256) void k_prep(const float* __restrict__ clean,
                                              const float* __restrict__ turb,
                                              const unsigned short* __restrict__ basisT,
                                              unsigned short* __restrict__ cnb,
                                              unsigned short* __restrict__ tnb,
                                              float* __restrict__ spat_part,
                                              float* __restrict__ freq_part) {
    __shared__ float xch[2][2][16][132];        // [src][trig][row][bin]  33 KB
    __shared__ unsigned short xraw[2][16][264]; // raw bf16 rows, +8 pad  16.5 KB
    __shared__ float invn[16][2];
    __shared__ float sp4[4], rbuf[4];

    const int t    = threadIdx.x;
    const int w    = t >> 6;
    const int lane = t & 63;
    const int rb   = blockIdx.x * 16;

    // ---- phase 1: coalesced load; norms; spatial partial; raw bf16 -> LDS ----
    float4 xc4[4], xt4[4];
    float dsq = 0.0f;
#pragma unroll
    for (int q = 0; q < 4; ++q) {
        const int row = q * 4 + w;           // wave w owns row q*4+w
        const float* pc = clean + (rb + row) * DDIM + lane * 4;
        const float* pt = turb  + (rb + row) * DDIM + lane * 4;
        xc4[q] = *(const float4*)pc;
        xt4[q] = *(const float4*)pt;
        const float4 a = xc4[q], b = xt4[q];
        dsq += (a.x - b.x) * (a.x - b.x) + (a.y - b.y) * (a.y - b.y)
             + (a.z - b.z) * (a.z - b.z) + (a.w - b.w) * (a.w - b.w);
        float nsc = a.x * a.x + a.y * a.y + a.z * a.z + a.w * a.w;
        float nst = b.x * b.x + b.y * b.y + b.z * b.z + b.w * b.w;
        nsc = wave_red(nsc);
        nst = wave_red(nst);
        if (lane == 0) {
            invn[row][0] = 1.0f / fmaxf(sqrtf(nsc), 1e-12f);
            invn[row][1] = 1.0f / fmaxf(sqrtf(nst), 1e-12f);
        }
        // raw bf16 into LDS (8B per store, lanes consecutive -> conflict-free)
        uint2 rc, rt;
        rc.x = bfbits(a.x) | (bfbits(a.y) << 16);
        rc.y = bfbits(a.z) | (bfbits(a.w) << 16);
        rt.x = bfbits(b.x) | (bfbits(b.y) << 16);
        rt.y = bfbits(b.z) | (bfbits(b.w) << 16);
        *(uint2*)&xraw[0][row][lane * 4] = rc;
        *(uint2*)&xraw[1][row][lane * 4] = rt;
    }
    dsq = wave_red(dsq);
    if (lane == 0) sp4[w] = dsq;
    __syncthreads();   // invn + xraw complete

    // ---- phase 2: normalized bf16 writes (8B coalesced global stores) ----
#pragma unroll
    for (int q = 0; q < 4; ++q) {
        const int row = q * 4 + w;
        const float ic = invn[row][0], it = invn[row][1];
        const float4 a = xc4[q], b = xt4[q];
        uint2 pc, pt;
        pc.x = bfbits(a.x * ic) | (bfbits(a.y * ic) << 16);
        pc.y = bfbits(a.z * ic) | (bfbits(a.w * ic) << 16);
        pt.x = bfbits(b.x * it) | (bfbits(b.y * it) << 16);
        pt.y = bfbits(b.z * it) | (bfbits(b.w * it) << 16);
        *(uint2*)(cnb + (rb + row) * DDIM + lane * 4) = pc;
        *(uint2*)(tnb + (rb + row) * DDIM + lane * 4) = pt;
    }

    // ---- phase 3: A-fragments from LDS ----
    const int srcw = w & 1;         // 0 clean, 1 turb
    const int trig = w >> 1;        // 0 cos, 1 sin
    bf16x8 a[8];
#pragma unroll
    for (int kk = 0; kk < 8; ++kk)
        a[kk] = *(const bf16x8*)&xraw[srcw][lane & 15][((lane >> 4) << 3) + kk * 32];

    // ---- phase 4: DFT MFMAs ----
    const unsigned short* bbase = basisT + (trig * 144 + (lane & 15)) * DDIM
                                + ((lane >> 4) << 3);
    const int lrow = (lane >> 4) << 2;
#pragma unroll 1
    for (int n = 0; n < 9; ++n) {
        f32x4 acc = (f32x4){0.f, 0.f, 0.f, 0.f};
#pragma unroll
        for (int kk = 0; kk < 8; ++kk) {
            bf16x8 b = *(const bf16x8*)(bbase + n * 16 * DDIM + kk * 32);
            acc = __builtin_amdgcn_mfma_f32_16x16x32_bf16(a[kk], b, acc, 0, 0, 0);
        }
        const int bin = n * 16 + (lane & 15);
        if (bin <= 128) {   // GUARD: n=8 covers bins 128..143; only 128 is real.
#pragma unroll
            for (int rr = 0; rr < 4; ++rr)
                xch[srcw][trig][lrow + rr][bin] = acc[rr];
        }
    }
    __syncthreads();

    // ---- phase 5: block reduce (|fft_c| - |fft_t|)^2, 16 rows x 129 bins ----
    {
        const int rr = t >> 4;
        float s = 0.0f;
        for (int b = (t & 15); b < NBINS; b += 16) {
            const float crc = xch[0][0][rr][b], cic = xch[0][1][rr][b];
            const float crt = xch[1][0][rr][b], cit = xch[1][1][rr][b];
            const float d = sqrtf(crc * crc + cic * cic)
                          - sqrtf(crt * crt + cit * cit);
            s += d * d;
        }
        s = wave_red(s);
        if (lane == 0) rbuf[w] = s;
    }
    __syncthreads();
    if (t == 0) {
        freq_part[blockIdx.x] = rbuf[0] + rbuf[1] + rbuf[2] + rbuf[3];
        spat_part[blockIdx.x] = sp4[0] + sp4[1] + sp4[2] + sp4[3];
    }
}

// ---------------------------------------------------------------------------
// Kernel 3: 128x128 bf16 MFMA GEMM — EXACT r13-measured config (53.7 us,
// VGPR 72). BK=64 single-buffer, swizzled staging, swapped-operand MFMA
// epilogue, supertile XCD swizzle, plain launch bounds.
// ---------------------------------------------------------------------------
#define BM 128
#define BN 128
#define BK 64

__global__ __launch_bounds__(256) void k_gemm(const unsigned short* __restrict__ cnb,
                                              const unsigned short* __restrict__ tnb,
                                              const int* __restrict__ sid,
                                              float* __restrict__ pall,
                                              float* __restrict__ ppos) {
    __shared__ unsigned short As[BM][BK];
    __shared__ unsigned short Bs[BN][BK];
    __shared__ float ps[2][BM][2];          // [colhalf][row][all|pos]
    __shared__ int sidI[BM], sidJ[BN];

    // Supertile XCD swizzle: bijective (4096%8==0), ~1 MB working set/XCD.
    const int bid = blockIdx.x;
    const int xcd = bid & 7;
    const int q   = bid >> 3;            // 0..511
    const int grp = q >> 6;              // jb supertile group 0..7
    const int r   = q & 63;
    const int ib  = xcd * 8 + (r >> 3);
    const int jb  = grp * 8 + (r & 7);
    const int i0  = ib * BM;
    const int j0  = jb * BN;

    const int t = threadIdx.x;
    if (t < 128) sidI[t] = sid[i0 + t];
    else         sidJ[t - 128] = sid[j0 + t - 128];

    const int wid  = t >> 6;
    const int lane = t & 63;
    const int wrow = (wid >> 1) * 64;
    const int wcol = (wid & 1) * 64;
    const int rx   = lane & 7;

    f32x4 acc[4][4];
#pragma unroll
    for (int m = 0; m < 4; ++m)
#pragma unroll
        for (int n = 0; n < 4; ++n)
            acc[m][n] = (f32x4){0.f, 0.f, 0.f, 0.f};

    for (int kt = 0; kt < DDIM / BK; ++kt) {
        // stage: linear LDS dest, inverse-swizzled global source
#pragma unroll
        for (int it = 0; it < 4; ++it) {
            const int g  = it * 256 + t;          // 16B granule 0..1023
            const int rr = g >> 3;
            const int sl = g & 7;
            const int sc = ((sl ^ (rr & 7)) << 3);
            gload_lds16(cnb + (i0 + rr) * DDIM + kt * BK + sc,
                        (char*)&As[0][0] + g * 16);
            gload_lds16(tnb + (j0 + rr) * DDIM + kt * BK + sc,
                        (char*)&Bs[0][0] + g * 16);
        }
        __syncthreads();   // drains vmcnt before reads
#pragma unroll
        for (int kk = 0; kk < BK / 32; ++kk) {
            const int kslot = kk * 4 + (lane >> 4);
            bf16x8 af[4], bfr[4];
#pragma unroll
            for (int m = 0; m < 4; ++m) {
                const int row = wrow + m * 16 + (lane & 15);
                af[m] = *(const bf16x8*)((const char*)&As[0][0]
                          + row * 128 + ((kslot ^ rx) << 4));
            }
#pragma unroll
            for (int n = 0; n < 4; ++n) {
                const int row = wcol + n * 16 + (lane & 15);
                bfr[n] = *(const bf16x8*)((const char*)&Bs[0][0]
                          + row * 128 + ((kslot ^ rx) << 4));
            }
            // SWAPPED: D layout -> lane&15 = cn row, in-lane r = tn col.
#pragma unroll
            for (int m = 0; m < 4; ++m)
#pragma unroll
                for (int n = 0; n < 4; ++n)
                    acc[m][n] = __builtin_amdgcn_mfma_f32_16x16x32_bf16(
                        bfr[n], af[m], acc[m][n], 0, 0, 0);
        }
        __syncthreads();   // all reads done before next stage overwrites
    }

    // epilogue: exp2 + mask in registers over (n,r); shfl_xor 16,32 only.
    const float C = (1.0f / 0.07f) * 1.442695041f;   // invT * log2(e)
#pragma unroll
    for (int m = 0; m < 4; ++m) {
        const int rowm = wrow + m * 16 + (lane & 15);   // this lane's row
        const int si = sidI[rowm];
        float ra = 0.0f, rp = 0.0f;
#pragma unroll
        for (int n = 0; n < 4; ++n) {
            const int cb = wcol + n * 16 + ((lane >> 4) << 2);
            const int4 sj4 = *(const int4*)&sidJ[cb];
            float e0 = exp2f(acc[m][n][0] * C);
            float e1 = exp2f(acc[m][n][1] * C);
            float e2 = exp2f(acc[m][n][2] * C);
            float e3 = exp2f(acc[m][n][3] * C);
            ra += e0 + e1 + e2 + e3;
            rp += (si == sj4.x) ? e0 : 0.0f;
            rp += (si == sj4.y) ? e1 : 0.0f;
            rp += (si == sj4.z) ? e2 : 0.0f;
            rp += (si == sj4.w) ? e3 : 0.0f;
        }
        ra += __shfl_xor(ra, 16, 64);
        ra += __shfl_xor(ra, 32, 64);
        rp += __shfl_xor(rp, 16, 64);
        rp += __shfl_xor(rp, 32, 64);
        if (lane < 16) {
            ps[wid & 1][wrow + m * 16 + lane][0] = ra;
            ps[wid & 1][wrow + m * 16 + lane][1] = rp;
        }
    }
    __syncthreads();
    if (t < BM) {
        const float sa = ps[0][t][0] + ps[1][t][0];
        const float sp = ps[0][t][1] + ps[1][t][1];
        pall[jb * NROWS + i0 + t] = sa;
        ppos[jb * NROWS + i0 + t] = sp;
    }
}

// ---------------------------------------------------------------------------
// Kernel 4: per-row sum over 64 j-block partials + log terms.
// ---------------------------------------------------------------------------
__global__ __launch_bounds__(256) void k_red(const float* __restrict__ pall,
                                             const float* __restrict__ ppos,
                                             float* __restrict__ contrib) {
    __shared__ float red[256];
    const int row = blockIdx.x * 256 + threadIdx.x;
    float sa = 0.0f, sp = 0.0f;
    for (int jb = 0; jb < 64; ++jb) {
        sa += pall[jb * NROWS + row];
        sp += ppos[jb * NROWS + row];
    }
    red[threadIdx.x] = logf(sa + 1e-8f) - logf(sp);
    __syncthreads();
#pragma unroll
    for (int s = 128; s > 0; s >>= 1) {
        if (threadIdx.x < s) red[threadIdx.x] += red[threadIdx.x + s];
        __syncthreads();
    }
    if (threadIdx.x == 0) contrib[blockIdx.x] = red[0];
}

// ---------------------------------------------------------------------------
// Kernel 5: fold all partials -> 4 outputs
// ---------------------------------------------------------------------------
__global__ __launch_bounds__(256) void k_final(const float* __restrict__ spat_part,
                                               const float* __restrict__ freq_part,
                                               const float* __restrict__ contrib,
                                               float* __restrict__ out) {
    __shared__ float reda[256], redb[256], redc[256];
    float a = 0.0f, b = 0.0f, c = 0.0f;
    for (int i = threadIdx.x; i < 512; i += 256) {
        a += spat_part[i];
        b += freq_part[i];
    }
    if (threadIdx.x < 32) c = contrib[threadIdx.x];
    reda[threadIdx.x] = a; redb[threadIdx.x] = b; redc[threadIdx.x] = c;
    __syncthreads();
#pragma unroll
    for (int s = 128; s > 0; s >>= 1) {
        if (threadIdx.x < s) {
            reda[threadIdx.x] += reda[threadIdx.x + s];
            redb[threadIdx.x] += redb[threadIdx.x + s];
            redc[threadIdx.x] += redc[threadIdx.x + s];
        }
        __syncthreads();
    }
    if (threadIdx.x == 0) {
        float spatial = reda[0] / (float)(NROWS * DDIM);
        float frequency = redb[0] / (float)(NROWS * NBINS);
        float contrastive = redc[0] / (float)NROWS;
        out[0] = spatial + frequency + 0.5f * contrastive;
        out[1] = spatial;
        out[2] = frequency;
        out[3] = contrastive;
    }
}

// ---------------------------------------------------------------------------
extern "C" void kernel_launch(void* const* d_in, const int* in_sizes, int n_in,
                              void* d_out, int out_size, void* d_ws, size_t ws_size,
                              hipStream_t stream) {
    const float* clean = (const float*)d_in[0];
    const float* turb  = (const float*)d_in[1];
    const int*   sids  = (const int*)d_in[2];

    char* ws = (char*)d_ws;
    unsigned short* cnb    = (unsigned short*)ws;                      // 4 MB
    unsigned short* tnb    = (unsigned short*)(ws + 4194304);          // 4 MB
    unsigned short* basisT = (unsigned short*)(ws + 8388608);          // 147 KB
    float* pall      = (float*)(ws + 8650752);                         // 2 MB
    float* ppos      = (float*)(ws + 10747904);                        // 2 MB
    float* spat_part = (float*)(ws + 12845056);                        // 2 KB
    float* freq_part = (float*)(ws + 12849152);                        // 2 KB
    float* contrib   = (float*)(ws + 12853248);                        // 128 B

    hipLaunchKernelGGL(k_basis, dim3(288), dim3(256), 0, stream, basisT);
    hipLaunchKernelGGL(k_prep, dim3(NROWS / 16), dim3(256), 0, stream,
                       clean, turb, basisT, cnb, tnb, spat_part, freq_part);
    hipLaunchKernelGGL(k_gemm, dim3(4096), dim3(256), 0, stream,
                       cnb, tnb, sids, pall, ppos);
    hipLaunchKernelGGL(k_red, dim3(NROWS / 256), dim3(256), 0, stream,
                       pall, ppos, contrib);
    hipLaunchKernelGGL(k_final, dim3(1), dim3(256), 0, stream,
                       spat_part, freq_part, contrib, (float*)d_out);
}

// Round 16
// 86.777 us; speedup vs baseline: 1.5029x; 1.0866x over previous
//
#include <hip/hip_runtime.h>

#define NROWS 8192
#define DDIM  256
#define NBINS 129

typedef float f32x4 __attribute__((ext_vector_type(4)));
typedef short bf16x8 __attribute__((ext_vector_type(8)));

__device__ __forceinline__ float wave_red(float v) {
#pragma unroll
    for (int m = 32; m; m >>= 1) v += __shfl_xor(v, m, 64);
    return v;
}

__device__ __forceinline__ unsigned bfbits(float f) {
    union { float f; unsigned u; } v; v.f = f;
    return (v.u + 0x7FFFu + ((v.u >> 16) & 1u)) >> 16;
}

__device__ __forceinline__ void gload_lds16(const void* g, void* l) {
    __builtin_amdgcn_global_load_lds((const __attribute__((address_space(1))) void*)g,
                                     (__attribute__((address_space(3))) void*)l,
                                     16, 0, 0);
}

// ---------------------------------------------------------------------------
// Kernel 1: DFT basis, transposed layout basisT[288][256] bf16.
// rows 0..128: cos(2*pi*n*k/256); rows 144..272: sin; others zero.
// ---------------------------------------------------------------------------
__global__ __launch_bounds__(256) void k_basis(unsigned short* __restrict__ basisT) {
    const int n = blockIdx.x;    // 0..287
    const int k = threadIdx.x;   // 0..255
    float v = 0.0f;
    const float step = 0.0245436926f;  // 2*pi/256
    if (n < 129)                  v = cosf(step * (float)((n * k) & 255));
    else if (n >= 144 && n < 273) v = sinf(step * (float)(((n - 144) * k) & 255));
    basisT[n * DDIM + k] = (unsigned short)bfbits(v);
}

// ---------------------------------------------------------------------------
// Kernel 2 (fused row+dft), NO-EXCHANGE version: each wave computes ALL FOUR
// (src x trig) DFT combos for its n-quarter -> magnitude diff fully in-lane.
//  - A-frags for clean AND turb in registers (64 VGPR), from LDS-staged
//    NORMALIZED bf16 (shared with the global write); magnitudes rescaled by
//    the row norm (FFT linearity) — same quantization as verified path.
//  - each basisT load feeds 2 MFMAs (2x reuse vs r15).
//  - no xch array (-33 KB LDS), no exchange barrier, no reduce pass.
//  - bins >128 read all-zero basis rows -> contribute 0 (no guard needed).
// ---------------------------------------------------------------------------
__global__ __launch_bounds__(256) void k_prep(const float* __restrict__ clean,
                                              const float* __restrict__ turb,
                                              const unsigned short* __restrict__ basisT,
                                              unsigned short* __restrict__ cnb,
                                              unsigned short* __restrict__ tnb,
                                              float* __restrict__ spat_part,
                                              float* __restrict__ freq_part) {
    __shared__ unsigned short xn[2][16][264];   // normalized bf16, +8 pad (16.5 KB)
    __shared__ float nrm[16][2];                // row norms (max(||x||,eps))
    __shared__ float sp4[4], rbuf[4];

    const int t    = threadIdx.x;
    const int w    = t >> 6;
    const int lane = t & 63;
    const int rb   = blockIdx.x * 16;

    // ---- phase 1: coalesced load; norms; spatial partial ----
    float4 xc4[4], xt4[4];
    float dsq = 0.0f;
#pragma unroll
    for (int q = 0; q < 4; ++q) {
        const int row = q * 4 + w;           // wave w owns row q*4+w
        const float* pc = clean + (rb + row) * DDIM + lane * 4;
        const float* pt = turb  + (rb + row) * DDIM + lane * 4;
        xc4[q] = *(const float4*)pc;
        xt4[q] = *(const float4*)pt;
        const float4 a = xc4[q], b = xt4[q];
        dsq += (a.x - b.x) * (a.x - b.x) + (a.y - b.y) * (a.y - b.y)
             + (a.z - b.z) * (a.z - b.z) + (a.w - b.w) * (a.w - b.w);
        float nsc = a.x * a.x + a.y * a.y + a.z * a.z + a.w * a.w;
        float nst = b.x * b.x + b.y * b.y + b.z * b.z + b.w * b.w;
        nsc = wave_red(nsc);
        nst = wave_red(nst);
        if (lane == 0) {
            nrm[row][0] = fmaxf(sqrtf(nsc), 1e-12f);
            nrm[row][1] = fmaxf(sqrtf(nst), 1e-12f);
        }
    }
    dsq = wave_red(dsq);
    if (lane == 0) sp4[w] = dsq;
    __syncthreads();   // nrm ready

    // ---- phase 2: normalized bf16 -> global AND LDS (one conversion) ----
#pragma unroll
    for (int q = 0; q < 4; ++q) {
        const int row = q * 4 + w;
        const float ic = 1.0f / nrm[row][0], it = 1.0f / nrm[row][1];
        const float4 a = xc4[q], b = xt4[q];
        uint2 pc, pt;
        pc.x = bfbits(a.x * ic) | (bfbits(a.y * ic) << 16);
        pc.y = bfbits(a.z * ic) | (bfbits(a.w * ic) << 16);
        pt.x = bfbits(b.x * it) | (bfbits(b.y * it) << 16);
        pt.y = bfbits(b.z * it) | (bfbits(b.w * it) << 16);
        *(uint2*)(cnb + (rb + row) * DDIM + lane * 4) = pc;
        *(uint2*)(tnb + (rb + row) * DDIM + lane * 4) = pt;
        *(uint2*)&xn[0][row][lane * 4] = pc;
        *(uint2*)&xn[1][row][lane * 4] = pt;
    }
    __syncthreads();   // xn ready

    // ---- phase 3: A-frags for BOTH sources from LDS ----
    const int fr = lane & 15;              // fragment row
    const int fc = (lane >> 4) << 3;       // fragment k-chunk (shorts)
    bf16x8 ac[8], at[8];
#pragma unroll
    for (int kk = 0; kk < 8; ++kk) {
        ac[kk] = *(const bf16x8*)&xn[0][fr][fc + kk * 32];
        at[kk] = *(const bf16x8*)&xn[1][fr][fc + kk * 32];
    }

    // per-lane norms for its 4 output rows (hoisted out of n-loop)
    const int lrow = (lane >> 4) << 2;
    float nc4[4], nt4[4];
#pragma unroll
    for (int r = 0; r < 4; ++r) {
        nc4[r] = nrm[lrow + r][0];
        nt4[r] = nrm[lrow + r][1];
    }

    // ---- phase 4: DFT MFMAs, all 4 combos per wave, n-quarter split ----
    // w=0: n 0..2, w=1: 3..4, w=2: 5..6, w=3: 7..8
    const int nlo = (w == 0) ? 0 : (w * 2 + 1);
    const int nhi = (w == 0) ? 3 : (w * 2 + 3);
    const unsigned short* bcb = basisT + fr * DDIM + fc;            // cos rows
    const unsigned short* bsb = basisT + (144 + fr) * DDIM + fc;    // sin rows

    float fsum = 0.0f;
#pragma unroll 1
    for (int n = nlo; n < nhi; ++n) {
        f32x4 acc_cc = (f32x4){0.f, 0.f, 0.f, 0.f};
        f32x4 acc_cs = (f32x4){0.f, 0.f, 0.f, 0.f};
        f32x4 acc_tc = (f32x4){0.f, 0.f, 0.f, 0.f};
        f32x4 acc_ts = (f32x4){0.f, 0.f, 0.f, 0.f};
#pragma unroll
        for (int kk = 0; kk < 8; ++kk) {
            const bf16x8 bc = *(const bf16x8*)(bcb + n * 16 * DDIM + kk * 32);
            const bf16x8 bs = *(const bf16x8*)(bsb + n * 16 * DDIM + kk * 32);
            acc_cc = __builtin_amdgcn_mfma_f32_16x16x32_bf16(ac[kk], bc, acc_cc, 0, 0, 0);
            acc_tc = __builtin_amdgcn_mfma_f32_16x16x32_bf16(at[kk], bc, acc_tc, 0, 0, 0);
            acc_cs = __builtin_amdgcn_mfma_f32_16x16x32_bf16(ac[kk], bs, acc_cs, 0, 0, 0);
            acc_ts = __builtin_amdgcn_mfma_f32_16x16x32_bf16(at[kk], bs, acc_ts, 0, 0, 0);
        }
        // in-lane magnitude diff; bins>128 have zero basis rows -> d = 0
#pragma unroll
        for (int r = 0; r < 4; ++r) {
            const float mc = nc4[r] * sqrtf(acc_cc[r] * acc_cc[r] + acc_cs[r] * acc_cs[r]);
            const float mt = nt4[r] * sqrtf(acc_tc[r] * acc_tc[r] + acc_ts[r] * acc_ts[r]);
            const float d = mc - mt;
            fsum += d * d;
        }
    }
    fsum = wave_red(fsum);
    if (lane == 0) rbuf[w] = fsum;
    __syncthreads();
    if (t == 0) {
        freq_part[blockIdx.x] = rbuf[0] + rbuf[1] + rbuf[2] + rbuf[3];
        spat_part[blockIdx.x] = sp4[0] + sp4[1] + sp4[2] + sp4[3];
    }
}

// ---------------------------------------------------------------------------
// Kernel 3: 128x128 bf16 MFMA GEMM — EXACT r13/r15-measured config (53.7 us,
// VGPR 72). BK=64 single-buffer, swizzled staging, swapped-operand MFMA
// epilogue, supertile XCD swizzle, plain launch bounds.
// ---------------------------------------------------------------------------
#define BM 128
#define BN 128
#define BK 64

__global__ __launch_bounds__(256) void k_gemm(const unsigned short* __restrict__ cnb,
                                              const unsigned short* __restrict__ tnb,
                                              const int* __restrict__ sid,
                                              float* __restrict__ pall,
                                              float* __restrict__ ppos) {
    __shared__ unsigned short As[BM][BK];
    __shared__ unsigned short Bs[BN][BK];
    __shared__ float ps[2][BM][2];          // [colhalf][row][all|pos]
    __shared__ int sidI[BM], sidJ[BN];

    // Supertile XCD swizzle: bijective (4096%8==0), ~1 MB working set/XCD.
    const int bid = blockIdx.x;
    const int xcd = bid & 7;
    const int q   = bid >> 3;            // 0..511
    const int grp = q >> 6;              // jb supertile group 0..7
    const int r   = q & 63;
    const int ib  = xcd * 8 + (r >> 3);
    const int jb  = grp * 8 + (r & 7);
    const int i0  = ib * BM;
    const int j0  = jb * BN;

    const int t = threadIdx.x;
    if (t < 128) sidI[t] = sid[i0 + t];
    else         sidJ[t - 128] = sid[j0 + t - 128];

    const int wid  = t >> 6;
    const int lane = t & 63;
    const int wrow = (wid >> 1) * 64;
    const int wcol = (wid & 1) * 64;
    const int rx   = lane & 7;

    f32x4 acc[4][4];
#pragma unroll
    for (int m = 0; m < 4; ++m)
#pragma unroll
        for (int n = 0; n < 4; ++n)
            acc[m][n] = (f32x4){0.f, 0.f, 0.f, 0.f};

    for (int kt = 0; kt < DDIM / BK; ++kt) {
        // stage: linear LDS dest, inverse-swizzled global source
#pragma unroll
        for (int it = 0; it < 4; ++it) {
            const int g  = it * 256 + t;          // 16B granule 0..1023
            const int rr = g >> 3;
            const int sl = g & 7;
            const int sc = ((sl ^ (rr & 7)) << 3);
            gload_lds16(cnb + (i0 + rr) * DDIM + kt * BK + sc,
                        (char*)&As[0][0] + g * 16);
            gload_lds16(tnb + (j0 + rr) * DDIM + kt * BK + sc,
                        (char*)&Bs[0][0] + g * 16);
        }
        __syncthreads();   // drains vmcnt before reads
#pragma unroll
        for (int kk = 0; kk < BK / 32; ++kk) {
            const int kslot = kk * 4 + (lane >> 4);
            bf16x8 af[4], bfr[4];
#pragma unroll
            for (int m = 0; m < 4; ++m) {
                const int row = wrow + m * 16 + (lane & 15);
                af[m] = *(const bf16x8*)((const char*)&As[0][0]
                          + row * 128 + ((kslot ^ rx) << 4));
            }
#pragma unroll
            for (int n = 0; n < 4; ++n) {
                const int row = wcol + n * 16 + (lane & 15);
                bfr[n] = *(const bf16x8*)((const char*)&Bs[0][0]
                          + row * 128 + ((kslot ^ rx) << 4));
            }
            // SWAPPED: D layout -> lane&15 = cn row, in-lane r = tn col.
#pragma unroll
            for (int m = 0; m < 4; ++m)
#pragma unroll
                for (int n = 0; n < 4; ++n)
                    acc[m][n] = __builtin_amdgcn_mfma_f32_16x16x32_bf16(
                        bfr[n], af[m], acc[m][n], 0, 0, 0);
        }
        __syncthreads();   // all reads done before next stage overwrites
    }

    // epilogue: exp2 + mask in registers over (n,r); shfl_xor 16,32 only.
    const float C = (1.0f / 0.07f) * 1.442695041f;   // invT * log2(e)
#pragma unroll
    for (int m = 0; m < 4; ++m) {
        const int rowm = wrow + m * 16 + (lane & 15);   // this lane's row
        const int si = sidI[rowm];
        float ra = 0.0f, rp = 0.0f;
#pragma unroll
        for (int n = 0; n < 4; ++n) {
            const int cb = wcol + n * 16 + ((lane >> 4) << 2);
            const int4 sj4 = *(const int4*)&sidJ[cb];
            float e0 = exp2f(acc[m][n][0] * C);
            float e1 = exp2f(acc[m][n][1] * C);
            float e2 = exp2f(acc[m][n][2] * C);
            float e3 = exp2f(acc[m][n][3] * C);
            ra += e0 + e1 + e2 + e3;
            rp += (si == sj4.x) ? e0 : 0.0f;
            rp += (si == sj4.y) ? e1 : 0.0f;
            rp += (si == sj4.z) ? e2 : 0.0f;
            rp += (si == sj4.w) ? e3 : 0.0f;
        }
        ra += __shfl_xor(ra, 16, 64);
        ra += __shfl_xor(ra, 32, 64);
        rp += __shfl_xor(rp, 16, 64);
        rp += __shfl_xor(rp, 32, 64);
        if (lane < 16) {
            ps[wid & 1][wrow + m * 16 + lane][0] = ra;
            ps[wid & 1][wrow + m * 16 + lane][1] = rp;
        }
    }
    __syncthreads();
    if (t < BM) {
        const float sa = ps[0][t][0] + ps[1][t][0];
        const float sp = ps[0][t][1] + ps[1][t][1];
        pall[jb * NROWS + i0 + t] = sa;
        ppos[jb * NROWS + i0 + t] = sp;
    }
}

// ---------------------------------------------------------------------------
// Kernel 4: per-row sum over 64 j-block partials + log terms.
// ---------------------------------------------------------------------------
__global__ __launch_bounds__(256) void k_red(const float* __restrict__ pall,
                                             const float* __restrict__ ppos,
                                             float* __restrict__ contrib) {
    __shared__ float red[256];
    const int row = blockIdx.x * 256 + threadIdx.x;
    float sa = 0.0f, sp = 0.0f;
    for (int jb = 0; jb < 64; ++jb) {
        sa += pall[jb * NROWS + row];
        sp += ppos[jb * NROWS + row];
    }
    red[threadIdx.x] = logf(sa + 1e-8f) - logf(sp);
    __syncthreads();
#pragma unroll
    for (int s = 128; s > 0; s >>= 1) {
        if (threadIdx.x < s) red[threadIdx.x] += red[threadIdx.x + s];
        __syncthreads();
    }
    if (threadIdx.x == 0) contrib[blockIdx.x] = red[0];
}

// ---------------------------------------------------------------------------
// Kernel 5: fold all partials -> 4 outputs
// ---------------------------------------------------------------------------
__global__ __launch_bounds__(256) void k_final(const float* __restrict__ spat_part,
                                               const float* __restrict__ freq_part,
                                               const float* __restrict__ contrib,
                                               float* __restrict__ out) {
    __shared__ float reda[256], redb[256], redc[256];
    float a = 0.0f, b = 0.0f, c = 0.0f;
    for (int i = threadIdx.x; i < 512; i += 256) {
        a += spat_part[i];
        b += freq_part[i];
    }
    if (threadIdx.x < 32) c = contrib[threadIdx.x];
    reda[threadIdx.x] = a; redb[threadIdx.x] = b; redc[threadIdx.x] = c;
    __syncthreads();
#pragma unroll
    for (int s = 128; s > 0; s >>= 1) {
        if (threadIdx.x < s) {
            reda[threadIdx.x] += reda[threadIdx.x + s];
            redb[threadIdx.x] += redb[threadIdx.x + s];
            redc[threadIdx.x] += redc[threadIdx.x + s];
        }
        __syncthreads();
    }
    if (threadIdx.x == 0) {
        float spatial = reda[0] / (float)(NROWS * DDIM);
        float frequency = redb[0] / (float)(NROWS * NBINS);
        float contrastive = redc[0] / (float)NROWS;
        out[0] = spatial + frequency + 0.5f * contrastive;
        out[1] = spatial;
        out[2] = frequency;
        out[3] = contrastive;
    }
}

// ---------------------------------------------------------------------------
extern "C" void kernel_launch(void* const* d_in, const int* in_sizes, int n_in,
                              void* d_out, int out_size, void* d_ws, size_t ws_size,
                              hipStream_t stream) {
    const float* clean = (const float*)d_in[0];
    const float* turb  = (const float*)d_in[1];
    const int*   sids  = (const int*)d_in[2];

    char* ws = (char*)d_ws;
    unsigned short* cnb    = (unsigned short*)ws;                      // 4 MB
    unsigned short* tnb    = (unsigned short*)(ws + 4194304);          // 4 MB
    unsigned short* basisT = (unsigned short*)(ws + 8388608);          // 147 KB
    float* pall      = (float*)(ws + 8650752);                         // 2 MB
    float* ppos      = (float*)(ws + 10747904);                        // 2 MB
    float* spat_part = (float*)(ws + 12845056);                        // 2 KB
    float* freq_part = (float*)(ws + 12849152);                        // 2 KB
    float* contrib   = (float*)(ws + 12853248);                        // 128 B

    hipLaunchKernelGGL(k_basis, dim3(288), dim3(256), 0, stream, basisT);
    hipLaunchKernelGGL(k_prep, dim3(NROWS / 16), dim3(256), 0, stream,
                       clean, turb, basisT, cnb, tnb, spat_part, freq_part);
    hipLaunchKernelGGL(k_gemm, dim3(4096), dim3(256), 0, stream,
                       cnb, tnb, sids, pall, ppos);
    hipLaunchKernelGGL(k_red, dim3(NROWS / 256), dim3(256), 0, stream,
                       pall, ppos, contrib);
    hipLaunchKernelGGL(k_final, dim3(1), dim3(256), 0, stream,
                       spat_part, freq_part, contrib, (float*)d_out);
}